// Round 4
// baseline (12635.968 us; speedup 1.0000x reference)
//
#include <hip/hip_runtime.h>
#include <stdint.h>

// ---------------------------------------------------------------------------
// DiffusionModel: 100 fused steps of x <- x + B*(x@Wx + t*csum + b) + s*noise
// Round-4 restructure: 1024 blocks x 512 thr, 32 rows/block -> per-thread
// state halved (xr 32 + acc 32 regs) so the whole live set fits in 128 VGPRs
// (launch_bounds(512,4)). Round-3 postmortem: 3.7 GB phantom WRITE_SIZE =
// scratch spills; spill working set (4.6 MB/XCD) thrashed L2 and evicted the
// 512 KB W blob -> 15 GB FETCH. Fitting in regs kills spills, doubles
// occupancy (16 waves/CU), and restores W's L2 residency.
// Noise: JAX threefry2x32-20 partitionable: counter=(0,e), bits=a^b.
// ---------------------------------------------------------------------------

typedef __attribute__((ext_vector_type(8))) short short8;
typedef __attribute__((ext_vector_type(4))) float f32x4;

#define XS_STRIDE 520          // bf16 elems per x-row in LDS (512+8 pad)
#define NSTEP 100

__device__ __forceinline__ uint32_t rotl32(uint32_t x, int r) {
  return (x << r) | (x >> (32 - r));   // -> v_alignbit_b32
}

// Threefry-2x32, 20 rounds, exactly as jax._src.prng.threefry2x32
__device__ __forceinline__ void tf_rounds(uint32_t k0, uint32_t k1, uint32_t k2,
                                          uint32_t& a, uint32_t& b) {
  a += k0; b += k1;
#define TFR(r) { a += b; b = rotl32(b, (r)); b ^= a; }
  TFR(13) TFR(15) TFR(26) TFR(6)   a += k1; b += k2 + 1u;
  TFR(17) TFR(29) TFR(16) TFR(24)  a += k2; b += k0 + 2u;
  TFR(13) TFR(15) TFR(26) TFR(6)   a += k0; b += k1 + 3u;
  TFR(17) TFR(29) TFR(16) TFR(24)  a += k1; b += k2 + 4u;
  TFR(13) TFR(15) TFR(26) TFR(6)   a += k2; b += k0 + 5u;
#undef TFR
}

// bits -> uniform[-0.99999994, 1) -> sqrt(2)*erfinv(u)  (XLA/Giles erfinv;
// log1p -> hw log of fma(u,-u,1): ~2ulp, irrelevant vs 1.6 threshold).
// Tail branch (|u|>0.9993, P~7e-4) kept as a real branch, not if-converted.
__device__ __forceinline__ float gauss_from_bits(uint32_t bits) {
  const float lo = __uint_as_float(0xBF7FFFFFu);   // nextafter(-1,0)
  float f = __uint_as_float((bits >> 9) | 0x3F800000u) - 1.0f;  // [0,1)
  float u = fmaxf(lo, fmaf(f, 2.0f, lo));
  float om = fmaf(u, -u, 1.0f);                    // 1-u^2 > 0
  float w = -__logf(om);
  float p;
  if (__builtin_expect(w < 5.0f, 1)) {
    float z = w - 2.5f;
    p =            2.81022636e-08f;
    p = fmaf(p, z, 3.43273939e-07f);
    p = fmaf(p, z, -3.5233877e-06f);
    p = fmaf(p, z, -4.39150654e-06f);
    p = fmaf(p, z, 0.00021858087f);
    p = fmaf(p, z, -0.00125372503f);
    p = fmaf(p, z, -0.00417768164f);
    p = fmaf(p, z, 0.246640727f);
    p = fmaf(p, z, 1.50140941f);
  } else {
    float z = sqrtf(w) - 3.0f;
    p =            -0.000200214257f;
    p = fmaf(p, z, 0.000100950558f);
    p = fmaf(p, z, 0.00134934322f);
    p = fmaf(p, z, -0.00367342844f);
    p = fmaf(p, z, 0.00573950773f);
    p = fmaf(p, z, -0.0076224613f);
    p = fmaf(p, z, 0.00943887047f);
    p = fmaf(p, z, 1.00167406f);
    p = fmaf(p, z, 2.83297682f);
  }
  return 1.41421356f * (p * u);   // sqrt(2) * erfinv(u)
}

// f32 -> bf16 RNE (bit trick)
__device__ __forceinline__ uint16_t f2bf(float f) {
  uint32_t u = __float_as_uint(f);
  u += 0x7FFFu + ((u >> 16) & 1u);
  return (uint16_t)(u >> 16);
}

// --------------------------------------------------------------------------
// Pre-pass 1: Wx (rows 0..511 of W) -> bf16 blob, UNPADDED [c][n][32]:
// chunk c holds k in [32c,32c+32); B-frag for (c,n,q) = 16B at n*64+q*16 B.
// --------------------------------------------------------------------------
__global__ void prep_w_kernel(const float* __restrict__ W, uint16_t* __restrict__ blob) {
  int id = blockIdx.x * 256 + threadIdx.x;
  if (id >= 512 * 512) return;
  int k = id >> 9;        // feature (K) index
  int n = id & 511;       // output col
  float v = W[k * 512 + n];
  int c = k >> 5, kk = k & 31;
  blob[c * 16384 + n * 32 + kk] = f2bf(v);
}

// Pre-pass 2: csum[n] = sum_j W[512+j][n]  (rank-1 t-embedding part)
__global__ void prep_csum_kernel(const float* __restrict__ W, float* __restrict__ csum) {
  int n = blockIdx.x * 256 + threadIdx.x;
  if (n >= 512) return;
  float s = 0.0f;
  for (int j = 0; j < 512; ++j) s += W[(512 + j) * 512 + n];
  csum[n] = s;
}

// --------------------------------------------------------------------------
// Main fused kernel. 1024 blocks x 512 threads (8 waves). Block b owns rows
// [32b, 32b+32). Wave w computes cols [64w, 64w+64) for both 16-row tiles.
// MFMA 16x16x32 bf16: A[m=lane&15][k=q*8+j] (from xs), B[k][n=lane&15]
// (direct global 16B coalesced load, L2-resident blob), C row=4q+reg.
// Step body barrier-free except the 2 barriers around the xs rewrite.
// --------------------------------------------------------------------------
__global__ __launch_bounds__(512, 4) void diffuse_kernel(
    const float* __restrict__ x0, const uint16_t* __restrict__ wblob,
    const float* __restrict__ csum, const float* __restrict__ bvec,
    float* __restrict__ out) {
  __shared__ alignas(16) uint16_t xs[32 * XS_STRIDE];   // 33280 B

  const int tid = threadIdx.x;
  const int l15 = tid & 15;
  const int q   = (tid >> 4) & 3;
  const int wv  = tid >> 6;        // wave 0..7
  const int blk = blockIdx.x;      // 0..1023

  int   ncol[4];
  float csr[4], br[4];
#pragma unroll
  for (int nt = 0; nt < 4; ++nt) {
    ncol[nt] = wv * 64 + nt * 16 + l15;
    csr[nt]  = csum[ncol[nt]];
    br[nt]   = bvec[ncol[nt]];
  }

  // fp32 master of x, C-layout: (mt,nt)[j] = local row 16mt+4q+j, col ncol[nt]
  f32x4 xr[2][4];
#pragma unroll
  for (int mt = 0; mt < 2; ++mt)
#pragma unroll
    for (int j = 0; j < 4; ++j) {
      int gr = blk * 32 + mt * 16 + q * 4 + j;
#pragma unroll
      for (int nt = 0; nt < 4; ++nt)
        xr[mt][nt][j] = x0[gr * 512 + ncol[nt]];
    }

  // initial bf16 image
#pragma unroll
  for (int mt = 0; mt < 2; ++mt)
#pragma unroll
    for (int j = 0; j < 4; ++j) {
      int m = mt * 16 + q * 4 + j;
#pragma unroll
      for (int nt = 0; nt < 4; ++nt)
        xs[m * XS_STRIDE + ncol[nt]] = f2bf(xr[mt][nt][j]);
    }

  const float sq2b = sqrtf(0.02f);   // sqrt(2*beta)
  const f32x4 vzero = {0.0f, 0.0f, 0.0f, 0.0f};

  for (int t = 0; t < NSTEP; ++t) {
    // key_t = fold_in(key(42), t) = threefry((0,42),(0,t))
    uint32_t kt0 = 0u, kt1 = (uint32_t)t;
    tf_rounds(0u, 42u, 42u ^ 0x1BD11BDAu, kt0, kt1);
    const uint32_t kk2 = kt0 ^ kt1 ^ 0x1BD11BDAu;

    __syncthreads();   // xs writes (init / prev step) visible to all waves

    f32x4 acc[2][4];
#pragma unroll
    for (int mt = 0; mt < 2; ++mt)
#pragma unroll
      for (int nt = 0; nt < 4; ++nt)
        acc[mt][nt] = vzero;

    // ---- K-loop: no barriers; B prefetched one chunk ahead ----
    short8 bf[4], bfn[4];
#pragma unroll
    for (int nt = 0; nt < 4; ++nt)
      bf[nt] = *(const short8*)(wblob + ncol[nt] * 32 + q * 8);   // chunk 0

    for (int c = 0; c < 16; ++c) {
      int cn = (c + 1) & 15;
#pragma unroll
      for (int nt = 0; nt < 4; ++nt)
        bfn[nt] = *(const short8*)(wblob + cn * 16384 + ncol[nt] * 32 + q * 8);
#pragma unroll
      for (int mt = 0; mt < 2; ++mt) {
        short8 af = *(const short8*)&xs[(mt * 16 + l15) * XS_STRIDE + c * 32 + q * 8];
#pragma unroll
        for (int nt = 0; nt < 4; ++nt)
          acc[mt][nt] = __builtin_amdgcn_mfma_f32_16x16x32_bf16(
              af, bf[nt], acc[mt][nt], 0, 0, 0);
      }
#pragma unroll
      for (int nt = 0; nt < 4; ++nt)
        bf[nt] = bfn[nt];
    }

    // ---- noise + update (VALU only, barrier-free; consumes acc early) ----
    const float tf = (float)t;
#pragma unroll
    for (int mt = 0; mt < 2; ++mt) {
#pragma unroll
      for (int nt = 0; nt < 4; ++nt) {
        const float tc = fmaf(tf, csr[nt], br[nt]);
        const uint32_t ebase =
            (uint32_t)((blk * 32 + mt * 16 + q * 4) * 512 + ncol[nt]);
#pragma unroll
        for (int j = 0; j < 4; ++j) {
          float sc = acc[mt][nt][j] + tc;
          float xv = fmaf(0.01f, sc, xr[mt][nt][j]);  // x + B*score (ref order)
          uint32_t a = 0u, b = ebase + (uint32_t)(j * 512);
          tf_rounds(kt0, kt1, kk2, a, b);
          float n = gauss_from_bits(a ^ b);
          xv = fmaf(sq2b, n, xv);                     // + s*noise
          xr[mt][nt][j] = xv;
        }
      }
    }

    __syncthreads();   // all waves done reading xs for this step

    // xs rewrite (fenced by barrier above + loop-top barrier)
#pragma unroll
    for (int mt = 0; mt < 2; ++mt)
#pragma unroll
      for (int j = 0; j < 4; ++j) {
        int m = mt * 16 + q * 4 + j;
#pragma unroll
        for (int nt = 0; nt < 4; ++nt)
          xs[m * XS_STRIDE + ncol[nt]] = f2bf(xr[mt][nt][j]);
      }
  }

  // final store (fp32)
#pragma unroll
  for (int mt = 0; mt < 2; ++mt)
#pragma unroll
    for (int j = 0; j < 4; ++j) {
      int gr = blk * 32 + mt * 16 + q * 4 + j;
#pragma unroll
      for (int nt = 0; nt < 4; ++nt)
        out[gr * 512 + ncol[nt]] = xr[mt][nt][j];
    }
}

extern "C" void kernel_launch(void* const* d_in, const int* in_sizes, int n_in,
                              void* d_out, int out_size, void* d_ws, size_t ws_size,
                              hipStream_t stream) {
  const float* x0 = (const float*)d_in[0];   // (32768, 512)
  const float* W  = (const float*)d_in[1];   // (1024, 512)
  const float* bv = (const float*)d_in[2];   // (512,)
  float* out = (float*)d_out;

  uint16_t* blob = (uint16_t*)d_ws;                     // 512 KB bf16 W-blob
  float* csum = (float*)((char*)d_ws + 16 * 16384 * 2); // +2 KB

  prep_w_kernel<<<dim3(1024), dim3(256), 0, stream>>>(W, blob);
  prep_csum_kernel<<<dim3(2), dim3(256), 0, stream>>>(W, csum);
  diffuse_kernel<<<dim3(1024), dim3(512), 0, stream>>>(x0, blob, csum, bv, out);
}

// Round 5
// 8647.955 us; speedup vs baseline: 1.4612x; 1.4612x over previous
//
#include <hip/hip_runtime.h>
#include <stdint.h>

// ---------------------------------------------------------------------------
// DiffusionModel: 100 fused steps of x <- x + B*(x@Wx + t*csum + b) + s*noise
// 1024 blocks x 512 thr, 32 rows/block; x fp32 master in regs (MFMA C-layout),
// bf16 image in LDS for A-frags; W bf16 blob streams global->VGPR (prefetch 1
// chunk) for B-frags. Noise: JAX threefry2x32-20 partitionable (ctr=(0,e),
// bits=a^b) + XLA/Giles erfinv.
//
// LAUNCH-BOUNDS ERRATA (R2-R4 measured): 2nd arg acts as BLOCKS/CU for 8-wave
// blocks: (512,2)->VGPR cap 128, (512,4)->cap 64. R4's cap-64 forced ~50
// dwords/thread of scratch spill -> 3.5 GB phantom WRITE_SIZE + L2 thrash
// (29 GB FETCH). This round: (512,2) [cap 128, live set ~120] + csum/bias
// moved to a 4 KB LDS table (-8 VGPRs of slack).
// ---------------------------------------------------------------------------

typedef __attribute__((ext_vector_type(8))) short short8;
typedef __attribute__((ext_vector_type(4))) float f32x4;

#define XS_STRIDE 520          // bf16 elems per x-row in LDS (512+8 pad)
#define NSTEP 100

__device__ __forceinline__ uint32_t rotl32(uint32_t x, int r) {
  return (x << r) | (x >> (32 - r));   // -> v_alignbit_b32
}

// Threefry-2x32, 20 rounds, exactly as jax._src.prng.threefry2x32
__device__ __forceinline__ void tf_rounds(uint32_t k0, uint32_t k1, uint32_t k2,
                                          uint32_t& a, uint32_t& b) {
  a += k0; b += k1;
#define TFR(r) { a += b; b = rotl32(b, (r)); b ^= a; }
  TFR(13) TFR(15) TFR(26) TFR(6)   a += k1; b += k2 + 1u;
  TFR(17) TFR(29) TFR(16) TFR(24)  a += k2; b += k0 + 2u;
  TFR(13) TFR(15) TFR(26) TFR(6)   a += k0; b += k1 + 3u;
  TFR(17) TFR(29) TFR(16) TFR(24)  a += k1; b += k2 + 4u;
  TFR(13) TFR(15) TFR(26) TFR(6)   a += k2; b += k0 + 5u;
#undef TFR
}

// bits -> uniform[-0.99999994, 1) -> sqrt(2)*erfinv(u)  (XLA/Giles erfinv;
// log1p -> hw log of fma(u,-u,1): ~2ulp, irrelevant vs 1.6 threshold).
__device__ __forceinline__ float gauss_from_bits(uint32_t bits) {
  const float lo = __uint_as_float(0xBF7FFFFFu);   // nextafter(-1,0)
  float f = __uint_as_float((bits >> 9) | 0x3F800000u) - 1.0f;  // [0,1)
  float u = fmaxf(lo, fmaf(f, 2.0f, lo));
  float om = fmaf(u, -u, 1.0f);                    // 1-u^2 > 0
  float w = -__logf(om);
  float p;
  if (__builtin_expect(w < 5.0f, 1)) {
    float z = w - 2.5f;
    p =            2.81022636e-08f;
    p = fmaf(p, z, 3.43273939e-07f);
    p = fmaf(p, z, -3.5233877e-06f);
    p = fmaf(p, z, -4.39150654e-06f);
    p = fmaf(p, z, 0.00021858087f);
    p = fmaf(p, z, -0.00125372503f);
    p = fmaf(p, z, -0.00417768164f);
    p = fmaf(p, z, 0.246640727f);
    p = fmaf(p, z, 1.50140941f);
  } else {
    float z = sqrtf(w) - 3.0f;
    p =            -0.000200214257f;
    p = fmaf(p, z, 0.000100950558f);
    p = fmaf(p, z, 0.00134934322f);
    p = fmaf(p, z, -0.00367342844f);
    p = fmaf(p, z, 0.00573950773f);
    p = fmaf(p, z, -0.0076224613f);
    p = fmaf(p, z, 0.00943887047f);
    p = fmaf(p, z, 1.00167406f);
    p = fmaf(p, z, 2.83297682f);
  }
  return 1.41421356f * (p * u);   // sqrt(2) * erfinv(u)
}

// f32 -> bf16 RNE (bit trick)
__device__ __forceinline__ uint16_t f2bf(float f) {
  uint32_t u = __float_as_uint(f);
  u += 0x7FFFu + ((u >> 16) & 1u);
  return (uint16_t)(u >> 16);
}

// --------------------------------------------------------------------------
// Pre-pass 1: Wx (rows 0..511 of W) -> bf16 blob, UNPADDED [c][n][32]:
// chunk c holds k in [32c,32c+32); B-frag for (c,n,q) = 16B at n*64+q*16 B.
// --------------------------------------------------------------------------
__global__ void prep_w_kernel(const float* __restrict__ W, uint16_t* __restrict__ blob) {
  int id = blockIdx.x * 256 + threadIdx.x;
  if (id >= 512 * 512) return;
  int k = id >> 9;        // feature (K) index
  int n = id & 511;       // output col
  float v = W[k * 512 + n];
  int c = k >> 5, kk = k & 31;
  blob[c * 16384 + n * 32 + kk] = f2bf(v);
}

// Pre-pass 2: csum[n] = sum_j W[512+j][n]  (rank-1 t-embedding part)
__global__ void prep_csum_kernel(const float* __restrict__ W, float* __restrict__ csum) {
  int n = blockIdx.x * 256 + threadIdx.x;
  if (n >= 512) return;
  float s = 0.0f;
  for (int j = 0; j < 512; ++j) s += W[(512 + j) * 512 + n];
  csum[n] = s;
}

// --------------------------------------------------------------------------
// Main fused kernel. 1024 blocks x 512 threads (8 waves). Block b owns rows
// [32b, 32b+32). Wave w computes cols [64w, 64w+64).
// MFMA 16x16x32 bf16: A[m=lane&15][k=q*8+j] (from xs), B[k][n=lane&15]
// (direct global 16B coalesced load, L2-resident blob), C row=4q+reg.
// Step body barrier-free except the 2 barriers around the xs rewrite.
// --------------------------------------------------------------------------
__global__ __launch_bounds__(512, 2) void diffuse_kernel(
    const float* __restrict__ x0, const uint16_t* __restrict__ wblob,
    const float* __restrict__ csum, const float* __restrict__ bvec,
    float* __restrict__ out) {
  __shared__ alignas(16) uint16_t xs[32 * XS_STRIDE];   // 33280 B
  __shared__ alignas(8) float2 cb[512];                 // 4096 B {csum, bias}

  const int tid = threadIdx.x;
  const int l15 = tid & 15;
  const int q   = (tid >> 4) & 3;
  const int wv  = tid >> 6;        // wave 0..7
  const int blk = blockIdx.x;      // 0..1023

  // per-column {csum, bias} table (one writer per column)
  cb[tid] = make_float2(csum[tid], bvec[tid]);

  int ncol[4];
#pragma unroll
  for (int nt = 0; nt < 4; ++nt)
    ncol[nt] = wv * 64 + nt * 16 + l15;

  // fp32 master of x, C-layout: (mt,nt)[j] = local row 16mt+4q+j, col ncol[nt]
  f32x4 xr[2][4];
#pragma unroll
  for (int mt = 0; mt < 2; ++mt)
#pragma unroll
    for (int j = 0; j < 4; ++j) {
      int gr = blk * 32 + mt * 16 + q * 4 + j;
#pragma unroll
      for (int nt = 0; nt < 4; ++nt)
        xr[mt][nt][j] = x0[gr * 512 + ncol[nt]];
    }

  // initial bf16 image
#pragma unroll
  for (int mt = 0; mt < 2; ++mt)
#pragma unroll
    for (int j = 0; j < 4; ++j) {
      int m = mt * 16 + q * 4 + j;
#pragma unroll
      for (int nt = 0; nt < 4; ++nt)
        xs[m * XS_STRIDE + ncol[nt]] = f2bf(xr[mt][nt][j]);
    }

  const float sq2b = sqrtf(0.02f);   // sqrt(2*beta)
  const f32x4 vzero = {0.0f, 0.0f, 0.0f, 0.0f};

  for (int t = 0; t < NSTEP; ++t) {
    // key_t = fold_in(key(42), t) = threefry((0,42),(0,t))  [uniform -> SALU]
    uint32_t kt0 = 0u, kt1 = (uint32_t)t;
    tf_rounds(0u, 42u, 42u ^ 0x1BD11BDAu, kt0, kt1);
    const uint32_t kk2 = kt0 ^ kt1 ^ 0x1BD11BDAu;

    __syncthreads();   // xs writes (init / prev step) visible to all waves

    f32x4 acc[2][4];
#pragma unroll
    for (int mt = 0; mt < 2; ++mt)
#pragma unroll
      for (int nt = 0; nt < 4; ++nt)
        acc[mt][nt] = vzero;

    // ---- K-loop: no barriers; B prefetched one chunk ahead ----
    short8 bf[4], bfn[4];
#pragma unroll
    for (int nt = 0; nt < 4; ++nt)
      bf[nt] = *(const short8*)(wblob + ncol[nt] * 32 + q * 8);   // chunk 0

    for (int c = 0; c < 16; ++c) {
      int cn = (c + 1) & 15;
#pragma unroll
      for (int nt = 0; nt < 4; ++nt)
        bfn[nt] = *(const short8*)(wblob + cn * 16384 + ncol[nt] * 32 + q * 8);
#pragma unroll
      for (int mt = 0; mt < 2; ++mt) {
        short8 af = *(const short8*)&xs[(mt * 16 + l15) * XS_STRIDE + c * 32 + q * 8];
#pragma unroll
        for (int nt = 0; nt < 4; ++nt)
          acc[mt][nt] = __builtin_amdgcn_mfma_f32_16x16x32_bf16(
              af, bf[nt], acc[mt][nt], 0, 0, 0);
      }
#pragma unroll
      for (int nt = 0; nt < 4; ++nt)
        bf[nt] = bfn[nt];
    }

    // ---- noise + update (VALU only, barrier-free; consumes acc early) ----
    const float tf = (float)t;
#pragma unroll
    for (int mt = 0; mt < 2; ++mt) {
#pragma unroll
      for (int nt = 0; nt < 4; ++nt) {
        const float2 cbv = cb[ncol[nt]];
        const float tc = fmaf(tf, cbv.x, cbv.y);
        const uint32_t ebase =
            (uint32_t)((blk * 32 + mt * 16 + q * 4) * 512 + ncol[nt]);
#pragma unroll
        for (int j = 0; j < 4; ++j) {
          float sc = acc[mt][nt][j] + tc;
          float xv = fmaf(0.01f, sc, xr[mt][nt][j]);  // x + B*score (ref order)
          uint32_t a = 0u, b = ebase + (uint32_t)(j * 512);
          tf_rounds(kt0, kt1, kk2, a, b);
          float n = gauss_from_bits(a ^ b);
          xv = fmaf(sq2b, n, xv);                     // + s*noise
          xr[mt][nt][j] = xv;
        }
      }
    }

    __syncthreads();   // all waves done reading xs for this step

    // xs rewrite (fenced by barrier above + loop-top barrier)
#pragma unroll
    for (int mt = 0; mt < 2; ++mt)
#pragma unroll
      for (int j = 0; j < 4; ++j) {
        int m = mt * 16 + q * 4 + j;
#pragma unroll
        for (int nt = 0; nt < 4; ++nt)
          xs[m * XS_STRIDE + ncol[nt]] = f2bf(xr[mt][nt][j]);
      }
  }

  // final store (fp32)
#pragma unroll
  for (int mt = 0; mt < 2; ++mt)
#pragma unroll
    for (int j = 0; j < 4; ++j) {
      int gr = blk * 32 + mt * 16 + q * 4 + j;
#pragma unroll
      for (int nt = 0; nt < 4; ++nt)
        out[gr * 512 + ncol[nt]] = xr[mt][nt][j];
    }
}

extern "C" void kernel_launch(void* const* d_in, const int* in_sizes, int n_in,
                              void* d_out, int out_size, void* d_ws, size_t ws_size,
                              hipStream_t stream) {
  const float* x0 = (const float*)d_in[0];   // (32768, 512)
  const float* W  = (const float*)d_in[1];   // (1024, 512)
  const float* bv = (const float*)d_in[2];   // (512,)
  float* out = (float*)d_out;

  uint16_t* blob = (uint16_t*)d_ws;                     // 512 KB bf16 W-blob
  float* csum = (float*)((char*)d_ws + 16 * 16384 * 2); // +2 KB

  prep_w_kernel<<<dim3(1024), dim3(256), 0, stream>>>(W, blob);
  prep_csum_kernel<<<dim3(2), dim3(256), 0, stream>>>(W, csum);
  diffuse_kernel<<<dim3(1024), dim3(512), 0, stream>>>(x0, blob, csum, bv, out);
}

// Round 6
// 7772.013 us; speedup vs baseline: 1.6258x; 1.1127x over previous
//
#include <hip/hip_runtime.h>
#include <stdint.h>

// ---------------------------------------------------------------------------
// DiffusionModel: 100 fused steps of x <- x + B*(x@Wx + t*csum + b) + s*noise
// 1024 blocks x 1024 thr (16 waves); block owns rows [32b,32b+32); wave w
// covers cols [32w,32w+32). x fp32 master in regs (MFMA C-layout), bf16 image
// in LDS for A-frags; W bf16 blob streams global->VGPR (1-chunk prefetch).
// Noise: JAX threefry2x32-20 partitionable (ctr=(0,e), bits=a^b) + XLA/Giles
// erfinv.
//
// REGISTER MODEL (R2-R5 measured): __launch_bounds__ 2nd arg = min waves/EU;
// total budget (VGPR+AGPR) = 512/arg2, and hipcc splits arch/acc roughly
// evenly when pressured: (512,2)->128+128 => 2 w/SIMD, occ 24%, AGPR-copy
// VALU bloat; (512,4)->64+64 => scratch spills (3.5 GB phantom writes).
// This round: live set cut to ~70 regs (16 elems/thread) so budget 128
// ((1024,4)) fits with headroom -> no spills, no AGPR traffic, 16 waves/CU.
// ---------------------------------------------------------------------------

typedef __attribute__((ext_vector_type(8))) short short8;
typedef __attribute__((ext_vector_type(4))) float f32x4;

#define XS_STRIDE 520          // bf16 elems per x-row in LDS (512+8 pad)
#define NSTEP 100

__device__ __forceinline__ uint32_t rotl32(uint32_t x, int r) {
  return (x << r) | (x >> (32 - r));   // -> v_alignbit_b32
}

// Threefry-2x32, 20 rounds, exactly as jax._src.prng.threefry2x32
__device__ __forceinline__ void tf_rounds(uint32_t k0, uint32_t k1, uint32_t k2,
                                          uint32_t& a, uint32_t& b) {
  a += k0; b += k1;
#define TFR(r) { a += b; b = rotl32(b, (r)); b ^= a; }
  TFR(13) TFR(15) TFR(26) TFR(6)   a += k1; b += k2 + 1u;
  TFR(17) TFR(29) TFR(16) TFR(24)  a += k2; b += k0 + 2u;
  TFR(13) TFR(15) TFR(26) TFR(6)   a += k0; b += k1 + 3u;
  TFR(17) TFR(29) TFR(16) TFR(24)  a += k1; b += k2 + 4u;
  TFR(13) TFR(15) TFR(26) TFR(6)   a += k2; b += k0 + 5u;
#undef TFR
}

// bits -> uniform[-0.99999994, 1) -> sqrt(2)*erfinv(u)  (XLA/Giles erfinv).
// w = -ln(1-u^2) via hw v_log_f32 (log2) with the ln2 scale and the -2.5
// poly shift folded into one fma; ~2ulp vs log1p, irrelevant at thr=1.6.
__device__ __forceinline__ float gauss_from_bits(uint32_t bits) {
  const float lo = __uint_as_float(0xBF7FFFFFu);   // nextafter(-1,0)
  float f = __uint_as_float((bits >> 9) | 0x3F800000u) - 1.0f;  // [0,1)
  float u = fmaxf(lo, fmaf(f, 2.0f, lo));
  float om = fmaf(u, -u, 1.0f);                    // 1-u^2 > 0
  float L = __log2f(om);                           // w = -ln2 * L
  float p;
  if (__builtin_expect(L > -7.2134752f, 1)) {      // w < 5
    float z = fmaf(-0.69314718f, L, -2.5f);        // w - 2.5
    p =            2.81022636e-08f;
    p = fmaf(p, z, 3.43273939e-07f);
    p = fmaf(p, z, -3.5233877e-06f);
    p = fmaf(p, z, -4.39150654e-06f);
    p = fmaf(p, z, 0.00021858087f);
    p = fmaf(p, z, -0.00125372503f);
    p = fmaf(p, z, -0.00417768164f);
    p = fmaf(p, z, 0.246640727f);
    p = fmaf(p, z, 1.50140941f);
  } else {
    float z = sqrtf(-0.69314718f * L) - 3.0f;
    p =            -0.000200214257f;
    p = fmaf(p, z, 0.000100950558f);
    p = fmaf(p, z, 0.00134934322f);
    p = fmaf(p, z, -0.00367342844f);
    p = fmaf(p, z, 0.00573950773f);
    p = fmaf(p, z, -0.0076224613f);
    p = fmaf(p, z, 0.00943887047f);
    p = fmaf(p, z, 1.00167406f);
    p = fmaf(p, z, 2.83297682f);
  }
  return 1.41421356f * (p * u);   // sqrt(2) * erfinv(u)
}

// f32 -> bf16 RNE (bit trick)
__device__ __forceinline__ uint16_t f2bf(float f) {
  uint32_t u = __float_as_uint(f);
  u += 0x7FFFu + ((u >> 16) & 1u);
  return (uint16_t)(u >> 16);
}

// --------------------------------------------------------------------------
// Pre-pass 1: Wx (rows 0..511 of W) -> bf16 blob, UNPADDED [c][n][32]:
// chunk c holds k in [32c,32c+32); B-frag for (c,n,q) = 16B at n*64+q*16 B.
// --------------------------------------------------------------------------
__global__ void prep_w_kernel(const float* __restrict__ W, uint16_t* __restrict__ blob) {
  int id = blockIdx.x * 256 + threadIdx.x;
  if (id >= 512 * 512) return;
  int k = id >> 9;        // feature (K) index
  int n = id & 511;       // output col
  float v = W[k * 512 + n];
  int c = k >> 5, kk = k & 31;
  blob[c * 16384 + n * 32 + kk] = f2bf(v);
}

// Pre-pass 2: csum[n] = sum_j W[512+j][n]  (rank-1 t-embedding part)
__global__ void prep_csum_kernel(const float* __restrict__ W, float* __restrict__ csum) {
  int n = blockIdx.x * 256 + threadIdx.x;
  if (n >= 512) return;
  float s = 0.0f;
  for (int j = 0; j < 512; ++j) s += W[(512 + j) * 512 + n];
  csum[n] = s;
}

// --------------------------------------------------------------------------
// Main fused kernel. MFMA 16x16x32 bf16: A[m=lane&15][k=q*8+j] (from xs),
// B[k][n=lane&15] (direct global 16B coalesced load), C row=4q+reg.
// Step body barrier-free except the 2 barriers around the xs rewrite.
// Per thread: mt in {0,1} (16-row tiles), nt in {0,1} (16-col tiles).
// --------------------------------------------------------------------------
__global__ __launch_bounds__(1024, 4) void diffuse_kernel(
    const float* __restrict__ x0, const uint16_t* __restrict__ wblob,
    const float* __restrict__ csum, const float* __restrict__ bvec,
    float* __restrict__ out) {
  __shared__ alignas(16) uint16_t xs[32 * XS_STRIDE];   // 33280 B
  __shared__ alignas(8) float2 cb[512];                 // 4096 B {csum, bias}

  const int tid = threadIdx.x;
  const int l15 = tid & 15;
  const int q   = (tid >> 4) & 3;
  const int wv  = tid >> 6;        // wave 0..15
  const int blk = blockIdx.x;      // 0..1023

  if (tid < 512) cb[tid] = make_float2(csum[tid], bvec[tid]);

  int ncol[2];
#pragma unroll
  for (int nt = 0; nt < 2; ++nt)
    ncol[nt] = wv * 32 + nt * 16 + l15;

  // fp32 master of x, C-layout: (mt,nt)[j] = local row 16mt+4q+j, col ncol[nt]
  f32x4 xr[2][2];
#pragma unroll
  for (int mt = 0; mt < 2; ++mt)
#pragma unroll
    for (int j = 0; j < 4; ++j) {
      int gr = blk * 32 + mt * 16 + q * 4 + j;
#pragma unroll
      for (int nt = 0; nt < 2; ++nt)
        xr[mt][nt][j] = x0[gr * 512 + ncol[nt]];
    }

  // initial bf16 image
#pragma unroll
  for (int mt = 0; mt < 2; ++mt)
#pragma unroll
    for (int j = 0; j < 4; ++j) {
      int m = mt * 16 + q * 4 + j;
#pragma unroll
      for (int nt = 0; nt < 2; ++nt)
        xs[m * XS_STRIDE + ncol[nt]] = f2bf(xr[mt][nt][j]);
    }

  const float sq2b = sqrtf(0.02f);   // sqrt(2*beta)
  const f32x4 vzero = {0.0f, 0.0f, 0.0f, 0.0f};

  for (int t = 0; t < NSTEP; ++t) {
    // key_t = fold_in(key(42), t) = threefry((0,42),(0,t))  [uniform -> SALU]
    uint32_t kt0 = 0u, kt1 = (uint32_t)t;
    tf_rounds(0u, 42u, 42u ^ 0x1BD11BDAu, kt0, kt1);
    const uint32_t kk2 = kt0 ^ kt1 ^ 0x1BD11BDAu;

    __syncthreads();   // xs (+cb at t=0) writes visible to all waves

    f32x4 acc[2][2];
#pragma unroll
    for (int mt = 0; mt < 2; ++mt)
#pragma unroll
      for (int nt = 0; nt < 2; ++nt)
        acc[mt][nt] = vzero;

    // ---- K-loop: no barriers; B prefetched one chunk ahead ----
    short8 bf[2], bfn[2];
#pragma unroll
    for (int nt = 0; nt < 2; ++nt)
      bf[nt] = *(const short8*)(wblob + ncol[nt] * 32 + q * 8);   // chunk 0

    for (int c = 0; c < 16; ++c) {
      int cn = (c + 1) & 15;
#pragma unroll
      for (int nt = 0; nt < 2; ++nt)
        bfn[nt] = *(const short8*)(wblob + cn * 16384 + ncol[nt] * 32 + q * 8);
#pragma unroll
      for (int mt = 0; mt < 2; ++mt) {
        short8 af = *(const short8*)&xs[(mt * 16 + l15) * XS_STRIDE + c * 32 + q * 8];
#pragma unroll
        for (int nt = 0; nt < 2; ++nt)
          acc[mt][nt] = __builtin_amdgcn_mfma_f32_16x16x32_bf16(
              af, bf[nt], acc[mt][nt], 0, 0, 0);
      }
#pragma unroll
      for (int nt = 0; nt < 2; ++nt)
        bf[nt] = bfn[nt];
    }

    // ---- noise + update (VALU only, barrier-free; consumes acc early) ----
    const float tf = (float)t;
#pragma unroll
    for (int mt = 0; mt < 2; ++mt) {
#pragma unroll
      for (int nt = 0; nt < 2; ++nt) {
        const float2 cbv = cb[ncol[nt]];
        const float tc = fmaf(tf, cbv.x, cbv.y);
        const uint32_t ebase =
            (uint32_t)((blk * 32 + mt * 16 + q * 4) * 512 + ncol[nt]);
#pragma unroll
        for (int j = 0; j < 4; ++j) {
          float sc = acc[mt][nt][j] + tc;
          float xv = fmaf(0.01f, sc, xr[mt][nt][j]);  // x + B*score (ref order)
          uint32_t a = 0u, b = ebase + (uint32_t)(j * 512);
          tf_rounds(kt0, kt1, kk2, a, b);
          float n = gauss_from_bits(a ^ b);
          xv = fmaf(sq2b, n, xv);                     // + s*noise
          xr[mt][nt][j] = xv;
        }
      }
    }

    __syncthreads();   // all waves done reading xs for this step

    // xs rewrite (fenced by barrier above + loop-top barrier)
#pragma unroll
    for (int mt = 0; mt < 2; ++mt)
#pragma unroll
      for (int j = 0; j < 4; ++j) {
        int m = mt * 16 + q * 4 + j;
#pragma unroll
        for (int nt = 0; nt < 2; ++nt)
          xs[m * XS_STRIDE + ncol[nt]] = f2bf(xr[mt][nt][j]);
      }
  }

  // final store (fp32)
#pragma unroll
  for (int mt = 0; mt < 2; ++mt)
#pragma unroll
    for (int j = 0; j < 4; ++j) {
      int gr = blk * 32 + mt * 16 + q * 4 + j;
#pragma unroll
      for (int nt = 0; nt < 2; ++nt)
        out[gr * 512 + ncol[nt]] = xr[mt][nt][j];
    }
}

extern "C" void kernel_launch(void* const* d_in, const int* in_sizes, int n_in,
                              void* d_out, int out_size, void* d_ws, size_t ws_size,
                              hipStream_t stream) {
  const float* x0 = (const float*)d_in[0];   // (32768, 512)
  const float* W  = (const float*)d_in[1];   // (1024, 512)
  const float* bv = (const float*)d_in[2];   // (512,)
  float* out = (float*)d_out;

  uint16_t* blob = (uint16_t*)d_ws;                     // 512 KB bf16 W-blob
  float* csum = (float*)((char*)d_ws + 16 * 16384 * 2); // +2 KB

  prep_w_kernel<<<dim3(1024), dim3(256), 0, stream>>>(W, blob);
  prep_csum_kernel<<<dim3(2), dim3(256), 0, stream>>>(W, csum);
  diffuse_kernel<<<dim3(1024), dim3(1024), 0, stream>>>(x0, blob, csum, bv, out);
}